// Round 10
// baseline (150.391 us; speedup 1.0000x reference)
//
#include <hip/hip_runtime.h>
#include <hip/hip_bf16.h>
#include <math.h>

// DotProductAttention: B=16, Q=2048, K=2048, D=128, fp32 in/out.
// Query-axis masking: rows q >= valid_lens[b] -> uniform softmax -> mean(V)
// (combine writes those rows exactly from fp32 V column sums).
//
// Round 10: prep ELIMINATED. flash_g stages its (b, 128-key seg) slice
// straight from fp32 K/V (in-register cvt + transpose + granule swizzle,
// ds_write, ONE barrier), computes V colsum during staging (atomicAdd, j==0),
// reads Q fp32 directly, then the barrier-free q-loop over active q-tiles.
// 3 dispatches total: memset(8KB) + flash_g + combine.
// All MFMA fragment/slot formulas verbatim from R5/R9 (HW-verified):
// 32x32x16, S^T slot-permutation pi = swap bits 2<->3; S^T C-regs ARE the
// PV A-fragment.
//
// LDS layouts (identical to R9 flash_q, verified):
//   Ks[kk][slot]: row kk (256B), granule G=d>>3 at slot (G&8)|((G&7)^(kk&7))
//   Vs[d][slot] : row d  (256B), granule G=kk>>3 at slot (G&8)|((G&7)^(d&7))
//
// ws: [0,8K) sumV | Po f16 16 planes (134.2MB) | Lb f32 16 planes (2MB)
//     total ~136.4MB; ws measured = 268.4MB (fillBuffer size, R9 rocprof).

#define Bn 16
#define Qn 2048
#define Kn 2048
#define Dn 128
#define SCALE 0.08838834764831845f  // 1/sqrt(128)

typedef _Float16 f16;
typedef _Float16 f16x8_t __attribute__((ext_vector_type(8)));
typedef float f32x16_t __attribute__((ext_vector_type(16)));

// valid_lens may be stored as int32 or int64. Sniff: odd words all zero -> 64.
__device__ __forceinline__ int load_vl(const int* __restrict__ vlp, int b) {
  bool is64 = true;
#pragma unroll
  for (int i = 1; i < 16; i += 2) is64 = is64 && (vlp[i] == 0);
  return is64 ? vlp[2 * b] : vlp[b];
}

// ---------------- flash_g: fused stage+convert+colsum, q-loop-outer ---------
// grid (J*16, Bn) block 256.  x = seg + 16*j -> both j-blocks of a slice land
// on the same XCD (lin%8 == seg%8) for K/V L2 reuse.

template <int J>
__global__ void __launch_bounds__(256, 2) flash_g(
    const float* __restrict__ Qg, const float* __restrict__ Kg,
    const float* __restrict__ Vg, const int* __restrict__ vlp,
    f16* __restrict__ Po, float* __restrict__ Lb, float* __restrict__ sv) {
  const int b = blockIdx.y;
  const int seg = blockIdx.x & 15;
  const int j = blockIdx.x >> 4;
  const int vl = load_vl(vlp, b);
  const int nq = (vl + 127) >> 7;  // active q-tiles
  const int k0 = seg * 128;

  __shared__ __align__(16) f16 Ks[128 * 128];  // 32 KB
  __shared__ __align__(16) f16 Vs[128 * 128];  // 32 KB

  const int tid = threadIdx.x;

  // ---- stage K slice: thread -> key row kk=tid>>1, half=tid&1, 8 granules
  {
    const int kk = tid >> 1, half = tid & 1;
    const float* kp = Kg + ((size_t)b * Kn + k0 + kk) * Dn + half * 64;
    f16* krow_p = Ks + kk * 128;
    const int kk7 = kk & 7;
#pragma unroll
    for (int i = 0; i < 8; i++) {
      const int G = half * 8 + i;  // d-granule 0..15
      float4 f0 = *(const float4*)(kp + i * 8);
      float4 f1 = *(const float4*)(kp + i * 8 + 4);
      f16x8_t o;
      o[0] = (f16)f0.x; o[1] = (f16)f0.y; o[2] = (f16)f0.z; o[3] = (f16)f0.w;
      o[4] = (f16)f1.x; o[5] = (f16)f1.y; o[6] = (f16)f1.z; o[7] = (f16)f1.w;
      const int gs = (G & 8) | ((G & 7) ^ kk7);
      *(f16x8_t*)(krow_p + gs * 8) = o;
    }
  }

  // ---- stage V slice (transposed) + colsum: thread -> d=tid>>1, half=tid&1
  {
    const int d = tid >> 1, half = tid & 1;
    const float* vp = Vg + ((size_t)b * Kn + k0 + half * 64) * Dn + d;
    f16* vrow_p = Vs + d * 128;
    const int d7 = d & 7;
    float colsum = 0.f;
#pragma unroll
    for (int i = 0; i < 8; i++) {
      const int G = half * 8 + i;  // kk-granule 0..15
      f16x8_t o;
#pragma unroll
      for (int e = 0; e < 8; e++) {
        float v = vp[(size_t)(i * 8 + e) * Dn];
        o[e] = (f16)v;
        colsum += v;
      }
      const int gs = (G & 8) | ((G & 7) ^ d7);
      *(f16x8_t*)(vrow_p + gs * 8) = o;
    }
    if (j == 0) atomicAdd(&sv[b * Dn + d], colsum);  // masked fast path input
  }
  __syncthreads();  // ONLY barrier: LDS read-only afterwards

  if (nq == 0) return;  // fully-masked batch: colsum done, combine handles out

  const int wave = tid >> 6, lane = tid & 63;
  const int H = lane >> 5, l5 = lane & 31;

  // pi = swap bits 2<->3: A-row slot l5 holds physical key pi(l5) [R5-verified]
  const int krow = (l5 & 0x13) | ((l5 & 4) << 1) | ((l5 & 8) >> 1);
  const int krow7 = krow & 7;

  for (int qt = j; qt < nq; qt += J) {
    const int q0 = qt << 7;
    const int qbase = q0 + wave * 32;
    if (qbase >= vl) continue;  // no barriers: waves free to skip
    const int q_lane = qbase + l5;
    const float sc = (q_lane >= vl) ? 0.f : SCALE;  // masked row: p=1

    // Q fragment (B-operand of S^T): lane = q-col l5, k-els d = 16s+8H+e
    f16x8_t qf[8];
    {
      const float* qp = Qg + ((size_t)b * Qn + q_lane) * Dn + 8 * H;
#pragma unroll
      for (int s = 0; s < 8; s++) {
        float4 f0 = *(const float4*)(qp + 16 * s);
        float4 f1 = *(const float4*)(qp + 16 * s + 4);
        f16x8_t q8;
        q8[0] = (f16)f0.x; q8[1] = (f16)f0.y; q8[2] = (f16)f0.z; q8[3] = (f16)f0.w;
        q8[4] = (f16)f1.x; q8[5] = (f16)f1.y; q8[6] = (f16)f1.z; q8[7] = (f16)f1.w;
        qf[s] = q8;
      }
    }

    f32x16_t O[4];
#pragma unroll
    for (int i = 0; i < 4; i++) O[i] = (f32x16_t)(0.f);
    float l_lane = 0.f;

#pragma unroll
    for (int sub = 0; sub < 4; sub++) {
      // S^T = K.Q^T over keys sub*32..+31   [formulas verbatim from R5]
      f32x16_t T = (f32x16_t)(0.f);
      const f16* krp = Ks + ((sub * 32 + krow) << 7);
#pragma unroll
      for (int s = 0; s < 8; s++) {
        const int G = 2 * s + H;
        const int gs = (G & 8) | ((G & 7) ^ krow7);
        f16x8_t kf = *(const f16x8_t*)(krp + (gs << 3));
        T = __builtin_amdgcn_mfma_f32_32x32x16_f16(kf, qf[s], T, 0, 0, 0);
      }

      // p = exp(s); C-regs are the PV A-fragment (key 16(r>>3)+8H+(r&7))
      f16x8_t pf0, pf1;
      float ls = 0.f;
#pragma unroll
      for (int r = 0; r < 8; r++) {
        float p = __expf(T[r] * sc);
        ls += p;
        pf0[r] = (f16)p;
      }
#pragma unroll
      for (int r = 8; r < 16; r++) {
        float p = __expf(T[r] * sc);
        ls += p;
        pf1[r - 8] = (f16)p;
      }
      l_lane += ls;

      // O += P.V : B-frags from swizzled Vs (d-row dt*32+l5, 256B rows)
#pragma unroll
      for (int dt = 0; dt < 4; dt++) {
        const f16* vrp = Vs + ((dt * 32 + l5) << 7);
        const int G0 = sub * 4 + H, G1 = sub * 4 + 2 + H;  // 0..15
        const int gs0 = (G0 & 8) | ((G0 & 7) ^ (l5 & 7));
        const int gs1 = (G1 & 8) | ((G1 & 7) ^ (l5 & 7));
        f16x8_t vf0 = *(const f16x8_t*)(vrp + (gs0 << 3));
        f16x8_t vf1 = *(const f16x8_t*)(vrp + (gs1 << 3));
        O[dt] = __builtin_amdgcn_mfma_f32_32x32x16_f16(pf0, vf0, O[dt], 0, 0, 0);
        O[dt] = __builtin_amdgcn_mfma_f32_32x32x16_f16(pf1, vf1, O[dt], 0, 0, 0);
      }
    }

    // epilogue for this q-tile: unnormalized partials
    float ll = l_lane + __shfl_xor(l_lane, 32);
    if (lane < 32) Lb[(size_t)(seg * Bn + b) * Qn + qbase + l5] = ll;

    f16* po = Po + ((size_t)(seg * Bn + b) * Qn + qbase) * Dn;
#pragma unroll
    for (int dt = 0; dt < 4; dt++) {
#pragma unroll
      for (int r = 0; r < 16; r++) {
        const int qrow = (r & 3) + 8 * (r >> 2) + 4 * H;  // PV C-layout row
        po[(size_t)qrow * Dn + dt * 32 + l5] = (f16)O[dt][r];
      }
    }
  }
}

// ---------------- combine: out = sum_s O_s / sum_s l_s; masked rows = mean(V)
// grid (32, 16) block 256; 64 q-rows per block, 8 d per thread.

template <int S>
__global__ void __launch_bounds__(256) combine_kernel(
    const f16* __restrict__ Po, const float* __restrict__ Lb,
    const float* __restrict__ sv, const int* __restrict__ vlp,
    float* __restrict__ Out) {
  const int b = blockIdx.y, q0 = blockIdx.x * 64;
  const int vl = load_vl(vlp, b);
  const int tid = threadIdx.x;

  __shared__ float linv[64];
  if (tid < 64) {
    float s = 0.f;
#pragma unroll
    for (int sg = 0; sg < S; sg++) s += Lb[(size_t)(sg * Bn + b) * Qn + q0 + tid];
    linv[tid] = 1.0f / s;
  }
  __syncthreads();

  const int row16 = tid >> 4;     // 0..15
  const int d8 = (tid & 15) * 8;  // 0..120
  const float invK = 1.0f / (float)Kn;
  float mv[8];
#pragma unroll
  for (int jj = 0; jj < 8; jj++) mv[jj] = sv[b * Dn + d8 + jj] * invK;

#pragma unroll
  for (int pass = 0; pass < 4; pass++) {
    const int row = pass * 16 + row16;
    const int q = q0 + row;
    float acc[8];
    if (q >= vl) {
#pragma unroll
      for (int jj = 0; jj < 8; jj++) acc[jj] = mv[jj];  // fp32-exact uniform
    } else {
#pragma unroll
      for (int jj = 0; jj < 8; jj++) acc[jj] = 0.f;
#pragma unroll
      for (int sg = 0; sg < S; sg++) {
        f16x8_t v = *(const f16x8_t*)(Po + ((size_t)(sg * Bn + b) * Qn + q) * Dn + d8);
#pragma unroll
        for (int jj = 0; jj < 8; jj++) acc[jj] += (float)v[jj];
      }
      const float li = linv[row];
#pragma unroll
      for (int jj = 0; jj < 8; jj++) acc[jj] *= li;
    }
    float4 o0 = make_float4(acc[0], acc[1], acc[2], acc[3]);
    float4 o1 = make_float4(acc[4], acc[5], acc[6], acc[7]);
    float* op = Out + ((size_t)b * Qn + q) * Dn + d8;
    *(float4*)op = o0;
    *(float4*)(op + 4) = o1;
  }
}

// ---------------- launch ----------------

extern "C" void kernel_launch(void* const* d_in, const int* in_sizes, int n_in,
                              void* d_out, int out_size, void* d_ws, size_t ws_size,
                              hipStream_t stream) {
  const float* Qg = (const float*)d_in[0];
  const float* Kg = (const float*)d_in[1];
  const float* Vg = (const float*)d_in[2];
  const int* vl = (const int*)d_in[3];
  float* Out = (float*)d_out;

  char* ws = (char*)d_ws;
  const size_t plane = (size_t)Bn * Qn * Dn * 2;  // 8.39 MB
  const size_t lplane = (size_t)Bn * Qn * 4;      // 128 KB

  float* sumV = (float*)ws;                 // 8 KB
  f16* Po = (f16*)(ws + 8192);              // 16 planes = 134.2 MB
  float* Lb = (float*)(ws + 8192 + 16 * plane);  // 2 MB
  // need = 8192 + 16*plane + 16*lplane ~ 136.4 MB; ws measured 268.4 MB (R9).

  hipMemsetAsync(sumV, 0, Bn * Dn * sizeof(float), stream);
  flash_g<2><<<dim3(32, Bn), 256, 0, stream>>>(Qg, Kg, Vg, vl, Po, Lb, sumV);
  combine_kernel<16><<<dim3(Qn / 64, Bn), 256, 0, stream>>>(Po, Lb, sumV, vl, Out);
}